// Round 4
// baseline (77.521 us; speedup 1.0000x reference)
//
#include <hip/hip_runtime.h>

// Projector: out[n][j][k] = scale * sum_t trilinear(vol, p(t)+63.5)
//   p(t) = dc + j_c[j]*u + k_c[k]*v + t_c[t]*ray,  j_c/k_c = idx-63.5
// Constants (X=Y=Z=128): n_depth=222, max_extent=96*sqrt(3), dt=2*me/221,
// scale=2*me/222.
//
// R4: degenerate-z fast path (this input: iz==k exactly) is load-bound, so:
//  - pack_kernel builds Q[xp][m][k] = (bf16 v[xp-1][m-1][k], bf16 v[xp-1][m][k])
//    in one uint32, with zero-padded border slices (xp in [0,130), m in [0,129)).
//    One 4B load yields BOTH y-corners; padding removes all OOB masks/clamps.
//  - inner loop: 2 loads + lerp bilinear (~19 VALU) vs R3's 4 loads + ~31 VALU.
//  - t-window clipped to [-0.995,127.995] so padded indices are always valid
//    (dropped edge samples carry weight < 0.005 -> error < 0.01, thr 0.985).
constexpr int ND = 222;
constexpr int QX = 129 * 128;            // 16512: x-slice stride in Q
constexpr int QTOT = 130 * 129 * 128;    // 2,146,560 elems = 8.59 MB

__global__ __launch_bounds__(256) void pack_kernel(
    const float* __restrict__ vol, unsigned* __restrict__ Q)
{
    const int idx = blockIdx.x * 256 + threadIdx.x;
    if (idx >= QTOT) return;
    const int k = idx & 127;
    const int row = idx >> 7;            // xp*129 + m
    const int xp = row / 129;
    const int m = row - xp * 129;
    const int xa = xp - 1;
    float lo = 0.0f, hi = 0.0f;
    if ((unsigned)xa < 128u) {
        const float* r = vol + xa * 16384 + k;
        if (m >= 1)   lo = r[(m - 1) << 7];
        if (m <= 127) hi = r[m << 7];
    }
    unsigned bl = __float_as_uint(lo); bl = (bl + 0x7FFF + ((bl >> 16) & 1)) >> 16;
    unsigned bh = __float_as_uint(hi); bh = (bh + 0x7FFF + ((bh >> 16) & 1)) >> 16;
    Q[idx] = bl | (bh << 16);
}

__global__ __launch_bounds__(512) void projector_kernel(
    const float* __restrict__ vol,
    const float* __restrict__ vecs,
    const unsigned* __restrict__ Q,
    float* __restrict__ out)
{
    const int rowid = blockIdx.x;          // n*128 + j
    const int n = rowid >> 7;
    const int j = rowid & 127;
    const int k = threadIdx.x & 127;
    const int th = threadIdx.x >> 7;       // t-quarter 0..3

    const float* vp = vecs + n * 12;
    const float rx = vp[0], ry = vp[1], rz = vp[2];
    const float dcx = vp[3], dcy = vp[4], dcz = vp[5];
    const float ux = vp[6], uy = vp[7], uz = vp[8];
    const float vx = vp[9], vy = vp[10], vz = vp[11];

    const float jc = (float)j - 63.5f;
    const float kc = (float)k - 63.5f;

    const float t0c = -166.2768775266122f;   // -max_extent
    const float dtc = 1.5047681223222824f;   // 2*me/221
    const float scale = 1.4979898876271372f; // 2*me/222

    __shared__ float part[4][128];

    const bool degen = (rz == 0.0f) & (uz == 0.0f) & (dcz == 0.0f) &
                       (vx == 0.0f) & (vy == 0.0f) & (vz == 1.0f);

    float acc = 0.0f;

    if (degen) {
        // Row-uniform 2D problem in x-y; z slice == k exactly (fz==0).
        const float bx = dcx + jc * ux + 63.5f;
        const float by = dcy + jc * uy + 63.5f;

        // t-window: both axes strictly inside (-0.995, 127.995) so that
        // x0,y0 in [-1,127] and padded indices xp,m in [0,128].
        float tlo = -1e30f, thi = 1e30f;
        const float bsv[2] = {bx, by};
        const float rsv[2] = {rx, ry};
        #pragma unroll
        for (int a = 0; a < 2; ++a) {
            const float b = bsv[a], r = rsv[a];
            if (fabsf(r) > 1e-8f) {
                const float inv = 1.0f / r;
                const float t1 = (-0.995f - b) * inv;
                const float t2 = (127.995f - b) * inv;
                tlo = fmaxf(tlo, fminf(t1, t2));
                thi = fminf(thi, fmaxf(t1, t2));
            } else if (b < -0.995f || b > 127.995f) {
                tlo = 1e30f; thi = -1e30f;
            }
        }
        int tb = (int)ceilf((tlo - t0c) / dtc);
        int te = (int)floorf((thi - t0c) / dtc);
        tb = max(tb, 0); te = min(te, ND - 1);

        // quarter the (block-uniform) window among th
        const int len = max(te - tb + 1, 0);
        const int q = (len + 3) >> 2;
        const int mtb = tb + th * q;
        const int mte = min(mtb + q - 1, te);

        const unsigned* Qk = Q + k;
        #pragma unroll 4
        for (int t = mtb; t <= mte; ++t) {
            const float tc = fmaf(dtc, (float)t, t0c);
            const float ix = fmaf(tc, rx, bx);
            const float iy = fmaf(tc, ry, by);
            const float x0f = floorf(ix);
            const float y0f = floorf(iy);
            const float fx = ix - x0f;
            const float fy = iy - y0f;
            const int xp = (int)x0f + 1;       // [0,128]
            const int m  = (int)y0f + 1;       // [0,128]
            const int base = xp * QX + (m << 7);
            const unsigned q0 = Qk[base];
            const unsigned q1 = Qk[base + QX];
            const float lo0 = __uint_as_float(q0 << 16);
            const float hi0 = __uint_as_float(q0 & 0xFFFF0000u);
            const float lo1 = __uint_as_float(q1 << 16);
            const float hi1 = __uint_as_float(q1 & 0xFFFF0000u);
            const float s0 = fmaf(fy, hi0 - lo0, lo0);   // y-lerp @ x0
            const float s1 = fmaf(fy, hi1 - lo1, lo1);   // y-lerp @ x0+1
            acc += fmaf(fx, s1 - s0, s0);                // x-lerp
        }
    } else {
        // General per-lane path (unused for this input): fp32 volume, masks.
        const float bx = dcx + jc * ux + kc * vx + 63.5f;
        const float by = dcy + jc * uy + kc * vy + 63.5f;
        const float bz = dcz + jc * uz + kc * vz + 63.5f;

        float tlo = -1e30f, thi = 1e30f;
        const float bsv[3] = {bx, by, bz};
        const float rsv[3] = {rx, ry, rz};
        #pragma unroll
        for (int a = 0; a < 3; ++a) {
            const float b = bsv[a], r = rsv[a];
            if (fabsf(r) > 1e-8f) {
                const float inv = 1.0f / r;
                const float t1 = (-1.01f - b) * inv;
                const float t2 = (128.01f - b) * inv;
                tlo = fmaxf(tlo, fminf(t1, t2));
                thi = fminf(thi, fmaxf(t1, t2));
            } else if (b < -1.01f || b > 128.01f) {
                tlo = 1e30f; thi = -1e30f;
            }
        }
        int tb = (int)ceilf((tlo - t0c) / dtc);
        int te = (int)floorf((thi - t0c) / dtc);
        const int q = (ND + 3) >> 2;           // 56
        tb = max(tb, th * q);
        te = min(te, min(th * q + q - 1, ND - 1));

        for (int t = tb; t <= te; ++t) {
            const float tc = fmaf(dtc, (float)t, t0c);
            const float ix = fmaf(tc, rx, bx);
            const float iy = fmaf(tc, ry, by);
            const float iz = fmaf(tc, rz, bz);
            const float x0f = floorf(ix), y0f = floorf(iy), z0f = floorf(iz);
            const float fx = ix - x0f, fy = iy - y0f, fz = iz - z0f;
            const int x0 = (int)x0f, y0 = (int)y0f, z0 = (int)z0f;
            const float wx0 = ((unsigned)x0 < 128u) ? (1.0f - fx) : 0.0f;
            const float wx1 = ((unsigned)(x0 + 1) < 128u) ? fx : 0.0f;
            const float wy0 = ((unsigned)y0 < 128u) ? (1.0f - fy) : 0.0f;
            const float wy1 = ((unsigned)(y0 + 1) < 128u) ? fy : 0.0f;
            const float wz0 = ((unsigned)z0 < 128u) ? (1.0f - fz) : 0.0f;
            const float wz1 = ((unsigned)(z0 + 1) < 128u) ? fz : 0.0f;
            const int xa = min(max(x0, 0), 127) << 14;
            const int xb = min(max(x0 + 1, 0), 127) << 14;
            const int ya = min(max(y0, 0), 127) << 7;
            const int yb = min(max(y0 + 1, 0), 127) << 7;
            const int za = min(max(z0, 0), 127);
            const int zb = min(max(z0 + 1, 0), 127);
            const float w00 = wx0 * wy0, w01 = wx0 * wy1;
            const float w10 = wx1 * wy0, w11 = wx1 * wy1;
            float s0 = w00 * vol[xa + ya + za];
            s0 = fmaf(w01, vol[xa + yb + za], s0);
            s0 = fmaf(w10, vol[xb + ya + za], s0);
            s0 = fmaf(w11, vol[xb + yb + za], s0);
            float s1 = w00 * vol[xa + ya + zb];
            s1 = fmaf(w01, vol[xa + yb + zb], s1);
            s1 = fmaf(w10, vol[xb + ya + zb], s1);
            s1 = fmaf(w11, vol[xb + yb + zb], s1);
            acc = fmaf(s0, wz0, acc);
            acc = fmaf(s1, wz1, acc);
        }
    }

    // reduce the 4 t-quarters (stride-1 LDS: conflict-free)
    if (th != 0) part[th][k] = acc;
    __syncthreads();
    if (th == 0) {
        const float s = acc + part[1][k] + part[2][k] + part[3][k];
        out[rowid * 128 + k] = s * scale;
    }
}

extern "C" void kernel_launch(void* const* d_in, const int* in_sizes, int n_in,
                              void* d_out, int out_size, void* d_ws, size_t ws_size,
                              hipStream_t stream) {
    const float* vol  = (const float*)d_in[0];   // (128,128,128) fp32
    const float* vecs = (const float*)d_in[1];   // (8,12) fp32
    float* out = (float*)d_out;                  // (8,128,128) fp32
    unsigned* Q = (unsigned*)d_ws;               // 8.59 MB packed bf16 pairs

    pack_kernel<<<(QTOT + 255) / 256, 256, 0, stream>>>(vol, Q);

    dim3 block(512);
    dim3 grid(8 * 128);                          // one block per (n,j) row
    projector_kernel<<<grid, block, 0, stream>>>(vol, vecs, Q, out);
}